// Round 5
// baseline (532.289 us; speedup 1.0000x reference)
//
#include <hip/hip_runtime.h>

static constexpr int cT = 1024;   // tokens
static constexpr int cH = 1024;   // hidden
static constexpr int cI = 2816;   // intermediate
static constexpr int cE = 16;     // experts
static constexpr int cK = 4;      // top-k

typedef __attribute__((ext_vector_type(8))) short bf16x8;
typedef __attribute__((ext_vector_type(4))) float f32x4;
typedef __attribute__((ext_vector_type(2))) unsigned uint2v;
typedef __attribute__((ext_vector_type(4))) unsigned uint4v;

__device__ __forceinline__ unsigned f2bf(float f) {
  unsigned u = __float_as_uint(f);
  return (u + 0x7FFFu + ((u >> 16) & 1u)) >> 16;   // RNE f32->bf16
}
__device__ __forceinline__ unsigned pack2(float lo, float hi) {
  return f2bf(lo) | (f2bf(hi) << 16);
}

// Two ds_read_b64 (stride-34-uint layout is 8B- but not 16B-aligned).
__device__ __forceinline__ bf16x8 ld_bfrag(const unsigned* p) {
  union { uint2v d[2]; bf16x8 v; } r;
  r.d[0] = *(const uint2v*)p;
  r.d[1] = *(const uint2v*)(p + 2);
  return r.v;
}

// ------------------------------------------------------------- x -> bf16 ----
__global__ __launch_bounds__(256) void xcast_kernel(
    const float* __restrict__ x, unsigned short* __restrict__ xb) {
  const int i = blockIdx.x * 256 + threadIdx.x;
  const float4* xv = (const float4*)x;
  const float4 a = xv[i * 2], b = xv[i * 2 + 1];
  uint4v o;
  o.x = pack2(a.x, a.y); o.y = pack2(a.z, a.w);
  o.z = pack2(b.x, b.y); o.w = pack2(b.z, b.w);
  ((uint4v*)xb)[i] = o;
}

// ---------------------------------------------------------------- router ----
__global__ __launch_bounds__(64) void router_kernel(
    const float* __restrict__ x, const float* __restrict__ Wg,
    int* __restrict__ topk_id, float* __restrict__ topk_w,
    int* __restrict__ counts) {
  const int t = blockIdx.x;
  const int l = threadIdx.x;

  float xa[16];
#pragma unroll
  for (int i = 0; i < 16; ++i) xa[i] = x[(size_t)t * cH + l + 64 * i];

  float lg[16];
#pragma unroll
  for (int e = 0; e < 16; ++e) {
    float s = 0.f;
#pragma unroll
    for (int i = 0; i < 16; ++i) s += xa[i] * Wg[(size_t)e * cH + l + 64 * i];
#pragma unroll
    for (int d = 1; d < 64; d <<= 1) s += __shfl_xor(s, d);
    lg[e] = s;
  }

  if (l == 0) {
    int ids[4]; float vals[4];
    unsigned taken = 0;
#pragma unroll
    for (int j = 0; j < 4; ++j) {
      float m = -1e30f; int mi = 0;
#pragma unroll
      for (int e = 0; e < 16; ++e) {
        bool better = !((taken >> e) & 1u) && lg[e] > m;
        if (better) { m = lg[e]; mi = e; }
      }
      taken |= 1u << mi; ids[j] = mi; vals[j] = m;
    }
    const float mx = vals[0];
    float s = 0.f;
#pragma unroll
    for (int j = 0; j < 4; ++j) { vals[j] = __expf(vals[j] - mx); s += vals[j]; }
    const float inv = 1.f / s;
#pragma unroll
    for (int j = 0; j < 4; ++j) {
      topk_id[t * 4 + j] = ids[j];
      topk_w[t * 4 + j] = vals[j] * inv;
      atomicAdd(&counts[ids[j]], 1);
    }
  }
}

__global__ void scan_kernel(const int* __restrict__ counts,
                            int* __restrict__ offsets) {
  if (threadIdx.x == 0 && blockIdx.x == 0) {
    int acc = 0;
    for (int e = 0; e < cE; ++e) { offsets[e] = acc; acc += counts[e]; }
    offsets[cE] = acc;
  }
}

__global__ __launch_bounds__(256) void scatter_kernel(
    const int* __restrict__ topk_id, const int* __restrict__ offsets,
    int* __restrict__ cursor, int* __restrict__ pair_token,
    int* __restrict__ pair_pos) {
  const int i = blockIdx.x * 256 + threadIdx.x;   // 0..4095
  const int t = i >> 2;
  const int e = topk_id[i];
  const int pos = offsets[e] + atomicAdd(&cursor[e], 1);
  pair_token[pos] = t;
  pair_pos[i] = pos;
}

// ---------------------------------------------------------------- gate+up ---
// R3 layouts (stride-34 LDS, row-major act) + depth-2 register prefetch with
// the schedule: load(kt+2) -> MFMA(kt) -> pack(kt+1) -> barrier.
__global__ __launch_bounds__(256, 3) void gateup_kernel(
    const unsigned short* __restrict__ xb, const float* __restrict__ gw,
    const float* __restrict__ uw, const int* __restrict__ offsets,
    const int* __restrict__ pair_token, unsigned short* __restrict__ act) {
  const int e = blockIdx.y;
  const int off = offsets[e];
  const int n_e = offsets[e + 1] - off;
  const int strip = blockIdx.x / 3;
  const int c0 = (blockIdx.x % 3) * 128;
  if (c0 >= n_e) return;
  const int nb = strip * 64;
  const int tid = threadIdx.x, l = tid & 63, w = tid >> 6;
  const int q = l & 15, h16 = l >> 4;

  __shared__ unsigned sB[2][2][2176];   // [buf][mat][col*34 + kpair]
  __shared__ int tokl[128];

  const int sa = tid >> 4, sc = tid & 15;
  const float* gb = gw + (size_t)e * cH * cI + nb + sc * 4;
  const float* ub = uw + (size_t)e * cH * cI + nb + sc * 4;

  float4 g0[4], u0[4], g1[4], u1[4];

#define GU_LD(G, U, KT)                                                       \
  _Pragma("unroll")                                                           \
  for (int j = 0; j < 4; ++j) {                                               \
    G[j] = *(const float4*)(gb + (size_t)((KT) * 64 + sa * 4 + j) * cI);      \
    U[j] = *(const float4*)(ub + (size_t)((KT) * 64 + sa * 4 + j) * cI);      \
  }

#define GU_PACK(BUF, G, U)                                                    \
  _Pragma("unroll")                                                           \
  for (int i = 0; i < 4; ++i) {                                               \
    uint2v pg, pu;                                                            \
    pg.x = pack2(G[0][i], G[1][i]); pg.y = pack2(G[2][i], G[3][i]);           \
    pu.x = pack2(U[0][i], U[1][i]); pu.y = pack2(U[2][i], U[3][i]);           \
    *(uint2v*)&sB[BUF][0][(sc * 4 + i) * 34 + sa * 2] = pg;                   \
    *(uint2v*)&sB[BUF][1][(sc * 4 + i) * 34 + sa * 2] = pu;                   \
  }

#define GU_MFMA(CUR, KT)                                                      \
  _Pragma("unroll")                                                           \
  for (int ks = 0; ks < 2; ++ks) {                                            \
    const bf16x8 a0 = *(const bf16x8*)(ap0 + (KT) * 64 + ks * 32);            \
    const bf16x8 a1 = *(const bf16x8*)(ap1 + (KT) * 64 + ks * 32);            \
    _Pragma("unroll")                                                         \
    for (int ni = 0; ni < 4; ++ni) {                                          \
      const int ba = (q + 16 * ni) * 34 + h16 * 4 + 16 * ks;                  \
      const bf16x8 bg = ld_bfrag(&sB[CUR][0][ba]);                            \
      const bf16x8 bu = ld_bfrag(&sB[CUR][1][ba]);                            \
      ag0[ni] = __builtin_amdgcn_mfma_f32_16x16x32_bf16(a0, bg, ag0[ni], 0, 0, 0); \
      ag1[ni] = __builtin_amdgcn_mfma_f32_16x16x32_bf16(a1, bg, ag1[ni], 0, 0, 0); \
      au0[ni] = __builtin_amdgcn_mfma_f32_16x16x32_bf16(a0, bu, au0[ni], 0, 0, 0); \
      au1[ni] = __builtin_amdgcn_mfma_f32_16x16x32_bf16(a1, bu, au1[ni], 0, 0, 0); \
    }                                                                         \
  }

  for (int m0 = c0; m0 < n_e; m0 += 384) {
    if (tid < 128) tokl[tid] = pair_token[off + min(m0 + tid, n_e - 1)];
    __syncthreads();
    const int rows = min(128, n_e - m0);

    const unsigned short* ap0 =
        xb + (size_t)tokl[min(w * 32 + q, rows - 1)] * cH + h16 * 8;
    const unsigned short* ap1 =
        xb + (size_t)tokl[min(w * 32 + 16 + q, rows - 1)] * cH + h16 * 8;

    f32x4 ag0[4], ag1[4], au0[4], au1[4];
#pragma unroll
    for (int ni = 0; ni < 4; ++ni) {
      ag0[ni] = (f32x4){0.f, 0.f, 0.f, 0.f}; ag1[ni] = (f32x4){0.f, 0.f, 0.f, 0.f};
      au0[ni] = (f32x4){0.f, 0.f, 0.f, 0.f}; au1[ni] = (f32x4){0.f, 0.f, 0.f, 0.f};
    }

    GU_LD(g0, u0, 0)
    GU_LD(g1, u1, 1)
    GU_PACK(0, g0, u0)
    __syncthreads();

    for (int kt = 0; kt < 16; kt += 2) {
      if (kt + 2 < 16) { GU_LD(g0, u0, kt + 2) }
      GU_MFMA(0, kt)
      GU_PACK(1, g1, u1)
      __syncthreads();
      if (kt + 3 < 16) { GU_LD(g1, u1, kt + 3) }
      GU_MFMA(1, kt + 1)
      if (kt + 2 < 16) {
        GU_PACK(0, g0, u0)
        __syncthreads();
      }
    }

    // epilogue: silu(g)*u -> bf16 act (row-major)
#define GU_EPI(MI, AGV, AUV)                                                  \
  _Pragma("unroll")                                                           \
  for (int j = 0; j < 4; ++j) {                                               \
    const int er = m0 + w * 32 + (MI) * 16 + h16 * 4 + j;                     \
    if (er < n_e) {                                                           \
      _Pragma("unroll")                                                       \
      for (int ni = 0; ni < 4; ++ni) {                                        \
        const float g = AGV[ni][j], u = AUV[ni][j];                           \
        const float v = (g / (1.f + __expf(-g))) * u;                         \
        act[(size_t)(off + er) * cI + nb + ni * 16 + q] =                     \
            (unsigned short)f2bf(v);                                          \
      }                                                                       \
    }                                                                         \
  }
    GU_EPI(0, ag0, au0)
    GU_EPI(1, ag1, au1)
  }
#undef GU_LD
#undef GU_PACK
#undef GU_MFMA
#undef GU_EPI
}

// ------------------------------------------------------------------ down ----
// BM=128 (4 waves m-split), BN=128 (8 H-strips -> act re-read 8x not 16x),
// BK=64. act staged via LDS with coalesced 128B row loads + XOR swizzle
// (slot' = slot ^ (row&7)); dw staged float4-coalesced into stride-34 layout.
// Depth-2 register prefetch, one barrier per K-tile.
__global__ __launch_bounds__(256, 2) void down_kernel(
    const unsigned short* __restrict__ act, const float* __restrict__ dw,
    const int* __restrict__ offsets, float* __restrict__ yp) {
  const int e = blockIdx.y;
  const int off = offsets[e];
  const int n_e = offsets[e + 1] - off;
  const int strip = blockIdx.x / 3;
  const int c0 = (blockIdx.x % 3) * 128;
  if (c0 >= n_e) return;
  const int nb = strip * 128;
  const int tid = threadIdx.x, l = tid & 63, w = tid >> 6;
  const int q = l & 15, h16 = l >> 4;
  constexpr int NT = cI / 64;                 // 44

  __shared__ unsigned sB[2][4352];            // dw bf16 [col*34 + kpair]
  __shared__ unsigned short sA[2][8192];      // act [row*64 + (slot^(row&7))*8]

  const int rg = tid >> 5, cg = tid & 31;     // dw staging
  const float* db = dw + (size_t)e * cI * cH + nb + cg * 4;

  const int sr = tid >> 3, ss = tid & 7;      // act staging
  const int wslot = (ss ^ (sr & 7)) << 3;

  const int rxor = q & 7;                     // A-read swizzle (rows % 8)
  const int r0base = (w * 32 + q) * 64;
  const int r1base = r0base + 16 * 64;

  float4 d0[8], d1[8];
  uint4v a0s[4], a1s[4];

#define DN_LDW(D, KT)                                                         \
  _Pragma("unroll")                                                           \
  for (int j = 0; j < 8; ++j)                                                 \
    D[j] = *(const float4*)(db + (size_t)((KT) * 64 + rg * 8 + j) * cH);

#define DN_LDA(A, KT)                                                         \
  _Pragma("unroll")                                                           \
  for (int rd = 0; rd < 4; ++rd)                                              \
    A[rd] = *(const uint4v*)(aptr[rd] + (KT) * 64);

#define DN_PACK(BUF, D, A)                                                    \
  _Pragma("unroll")                                                           \
  for (int i = 0; i < 4; ++i) {                                               \
    uint2v plo, phi;                                                          \
    plo.x = pack2(D[0][i], D[1][i]); plo.y = pack2(D[2][i], D[3][i]);         \
    phi.x = pack2(D[4][i], D[5][i]); phi.y = pack2(D[6][i], D[7][i]);         \
    *(uint2v*)&sB[BUF][(cg * 4 + i) * 34 + rg * 4] = plo;                     \
    *(uint2v*)&sB[BUF][(cg * 4 + i) * 34 + rg * 4 + 2] = phi;                 \
  }                                                                           \
  _Pragma("unroll")                                                           \
  for (int rd = 0; rd < 4; ++rd)                                              \
    *(uint4v*)&sA[BUF][(sr + rd * 32) * 64 + wslot] = A[rd];

#define DN_MFMA(CUR)                                                          \
  _Pragma("unroll")                                                           \
  for (int ks = 0; ks < 2; ++ks) {                                            \
    const int sl = ((h16 + 4 * ks) ^ rxor) << 3;                              \
    const bf16x8 a0 = *(const bf16x8*)&sA[CUR][r0base + sl];                  \
    const bf16x8 a1 = *(const bf16x8*)&sA[CUR][r1base + sl];                  \
    _Pragma("unroll")                                                         \
    for (int ni = 0; ni < 8; ++ni) {                                          \
      const bf16x8 b = ld_bfrag(&sB[CUR][(q + 16 * ni) * 34 + h16 * 4 + 16 * ks]); \
      ac0[ni] = __builtin_amdgcn_mfma_f32_16x16x32_bf16(a0, b, ac0[ni], 0, 0, 0);  \
      ac1[ni] = __builtin_amdgcn_mfma_f32_16x16x32_bf16(a1, b, ac1[ni], 0, 0, 0);  \
    }                                                                         \
  }

  for (int m0 = c0; m0 < n_e; m0 += 384) {
    const unsigned short* aptr[4];
#pragma unroll
    for (int rd = 0; rd < 4; ++rd) {
      const int p = off + min(m0 + sr + rd * 32, n_e - 1);
      aptr[rd] = act + (size_t)p * cI + ss * 8;
    }

    f32x4 ac0[8], ac1[8];
#pragma unroll
    for (int ni = 0; ni < 8; ++ni) {
      ac0[ni] = (f32x4){0.f, 0.f, 0.f, 0.f};
      ac1[ni] = (f32x4){0.f, 0.f, 0.f, 0.f};
    }

    DN_LDW(d0, 0) DN_LDA(a0s, 0)
    DN_LDW(d1, 1) DN_LDA(a1s, 1)
    DN_PACK(0, d0, a0s)
    __syncthreads();

    for (int kt = 0; kt < NT; kt += 2) {
      if (kt + 2 < NT) { DN_LDW(d0, kt + 2) DN_LDA(a0s, kt + 2) }
      DN_MFMA(0)
      DN_PACK(1, d1, a1s)
      __syncthreads();
      if (kt + 3 < NT) { DN_LDW(d1, kt + 3) DN_LDA(a1s, kt + 3) }
      DN_MFMA(1)
      if (kt + 2 < NT) {
        DN_PACK(0, d0, a0s)
        __syncthreads();
      }
    }

#define DN_EPI(MI, ACV)                                                       \
  _Pragma("unroll")                                                           \
  for (int j = 0; j < 4; ++j) {                                               \
    const int er = m0 + w * 32 + (MI) * 16 + h16 * 4 + j;                     \
    if (er < n_e) {                                                           \
      _Pragma("unroll")                                                       \
      for (int ni = 0; ni < 8; ++ni)                                          \
        yp[(size_t)(off + er) * cH + nb + ni * 16 + q] = ACV[ni][j];          \
    }                                                                         \
  }
    DN_EPI(0, ac0)
    DN_EPI(1, ac1)

    if (m0 + 384 < n_e) __syncthreads();
  }
#undef DN_LDW
#undef DN_LDA
#undef DN_PACK
#undef DN_MFMA
#undef DN_EPI
}

// --------------------------------------------------------------- combine ----
__global__ __launch_bounds__(256) void combine_kernel(
    const float* __restrict__ yp, const int* __restrict__ pair_pos,
    const float* __restrict__ topk_w, float* __restrict__ out) {
  const int t = blockIdx.x;
  const int cb = threadIdx.x * 4;
  float4 s = make_float4(0.f, 0.f, 0.f, 0.f);
#pragma unroll
  for (int j = 0; j < 4; ++j) {
    const int pos = pair_pos[t * 4 + j];
    const float wj = topk_w[t * 4 + j];
    const float4 v = *(const float4*)(yp + (size_t)pos * cH + cb);
    s.x += wj * v.x; s.y += wj * v.y; s.z += wj * v.z; s.w += wj * v.w;
  }
  *(float4*)(out + (size_t)t * cH + cb) = s;
}

// ---------------------------------------------------------------- launch ----
extern "C" void kernel_launch(void* const* d_in, const int* in_sizes, int n_in,
                              void* d_out, int out_size, void* d_ws,
                              size_t ws_size, hipStream_t stream) {
  (void)in_sizes; (void)n_in; (void)out_size; (void)ws_size;
  const float* x = (const float*)d_in[0];
  const float* Wg = (const float*)d_in[1];
  const float* gw = (const float*)d_in[2];
  const float* uw = (const float*)d_in[3];
  const float* dw = (const float*)d_in[4];
  float* out = (float*)d_out;

  char* ws = (char*)d_ws;
  int* counts     = (int*)(ws + 0);          // 16
  int* cursor     = (int*)(ws + 64);         // 16
  int* offsets    = (int*)(ws + 128);        // 17
  int* topk_id    = (int*)(ws + 256);        // 4096
  float* topk_w   = (float*)(ws + 256 + 16384);
  int* pair_token = (int*)(ws + 256 + 32768);
  int* pair_pos   = (int*)(ws + 256 + 49152);
  unsigned short* act = (unsigned short*)(ws + 65792);           // 23.07 MB
  unsigned short* xb  = (unsigned short*)(ws + 65792 + (size_t)4096 * 2816 * 2);
  float* yp = (float*)(ws + 65792 + (size_t)4096 * 2816 * 2 + (size_t)cT * cH * 2);

  hipMemsetAsync(ws, 0, 128, stream);        // counts + cursor

  xcast_kernel<<<cT * cH / (256 * 8), 256, 0, stream>>>(x, xb);
  router_kernel<<<cT, 64, 0, stream>>>(x, Wg, topk_id, topk_w, counts);
  scan_kernel<<<1, 1, 0, stream>>>(counts, offsets);
  scatter_kernel<<<cT * cK / 256, 256, 0, stream>>>(topk_id, offsets, cursor,
                                                    pair_token, pair_pos);
  gateup_kernel<<<dim3(44 * 3, cE), 256, 0, stream>>>(xb, gw, uw, offsets,
                                                      pair_token, act);
  down_kernel<<<dim3(8 * 3, cE), 256, 0, stream>>>(act, dw, offsets, yp);
  combine_kernel<<<cT, 256, 0, stream>>>(yp, pair_pos, topk_w, out);
}